// Round 16
// baseline (114.982 us; speedup 1.0000x reference)
//
#include <hip/hip_runtime.h>
#include <hip/hip_bf16.h>
#include <cstdint>
#include <cstddef>

#define B_DIM 2048
#define D_DIM 512
#define NROWS 12288        // 6B rows of z
#define HALF  6144         // 3B
#define NT64  192          // 64-row tiles per dim
#define NPAIR64 18528      // 192*193/2 upper-tri tiles = 8 * 2316
#define EXP_SCALE 2.8853900817779268f   // log2(e)/TEMP, TEMP=0.5

typedef __attribute__((ext_vector_type(4))) float f32x4;
typedef __attribute__((ext_vector_type(8))) int i32x8;

// ---- merged gather: f -> A8 fp8 fragment-image (16x16 map), W*64 -> W8 ----
// off(r,k) = (r>>7)*131072 + (k>>7)*16384 + ((r>>4)&7)*2048
//            + ((k>>5)&3)*512 + (r&15)*32 + (k&31)
__global__ __launch_bounds__(256) void gather_fp8(
    const float* __restrict__ f_seq, const float* __restrict__ f_spa,
    const float* __restrict__ W,
    unsigned char* __restrict__ A8, unsigned char* __restrict__ W8) {
  int gidx = blockIdx.x * 256 + threadIdx.x;
  if (blockIdx.x < 1536) {
    int r = gidx >> 5;          // row 0..12287
    int c = gidx & 31;          // 32-elem k-chunk
    int k0 = c << 5;
    const float* f = (r < HALF) ? f_spa : f_seq;
    int rr = (r < HALF) ? r : r - HALF;
    int p = rr >> 11;
    int i = rr & 2047;
    int sel = (p == 2) ? 3 : p;
    const float* src = (k0 < D_DIM) ? f + ((size_t)i * 4 + sel) * D_DIM + k0
                                    : f + ((size_t)i * 4 + 2) * D_DIM + (k0 - D_DIM);
    unsigned int d[8];
#pragma unroll
    for (int q = 0; q < 8; ++q) {
      float4 x = *(const float4*)(src + 4 * q);
      int pk = __builtin_amdgcn_cvt_pk_fp8_f32(x.x, x.y, 0, 0);
      pk     = __builtin_amdgcn_cvt_pk_fp8_f32(x.z, x.w, pk, 1);
      d[q] = (unsigned int)pk;
    }
    size_t off = (size_t)(r >> 7) * 131072 + (size_t)(c >> 2) * 16384 +
                 (size_t)(((r >> 4) & 7) * 2048 + (c & 3) * 512 + (r & 15) * 32);
    *(uint4*)(A8 + off)      = (uint4){d[0], d[1], d[2], d[3]};
    *(uint4*)(A8 + off + 16) = (uint4){d[4], d[5], d[6], d[7]};
  } else {
    int widx = gidx - 1536 * 256;   // 0..16383
    int n = widx >> 5;              // 0..511
    int c = widx & 31;
    int k0 = c << 5;
    unsigned int d[8];
#pragma unroll
    for (int q = 0; q < 8; ++q) {
      float a0 = W[(size_t)(k0 + 4 * q + 0) * 512 + n] * 64.0f;
      float a1 = W[(size_t)(k0 + 4 * q + 1) * 512 + n] * 64.0f;
      float a2 = W[(size_t)(k0 + 4 * q + 2) * 512 + n] * 64.0f;
      float a3 = W[(size_t)(k0 + 4 * q + 3) * 512 + n] * 64.0f;
      int pk = __builtin_amdgcn_cvt_pk_fp8_f32(a0, a1, 0, 0);
      pk     = __builtin_amdgcn_cvt_pk_fp8_f32(a2, a3, pk, 1);
      d[q] = (unsigned int)pk;
    }
    size_t off = (size_t)(n >> 7) * 131072 + (size_t)(c >> 2) * 16384 +
                 (size_t)(((n >> 4) & 7) * 2048 + (c & 3) * 512 + (n & 15) * 32);
    *(uint4*)(W8 + off)      = (uint4){d[0], d[1], d[2], d[3]};
    *(uint4*)(W8 + off + 16) = (uint4){d[4], d[5], d[6], d[7]};
  }
}

// ---- projection GEMM fp8 MX: 1-wave blocks, 64x64 tile, acc[4][4] ----
// v = A @ W^T * 2^-6 + b (bf16 out). Grid (8, 192), block 64.
__global__ __launch_bounds__(64) void proj_fp8(
    const unsigned char* __restrict__ A8, const unsigned char* __restrict__ W8,
    const float* __restrict__ bvec, __hip_bfloat16* __restrict__ v) {
  int bn = blockIdx.x;        // 0..7   (64-col group)
  int bm = blockIdx.y;        // 0..191 (64-row tile)
  int lane = threadIdx.x & 63;
  int g = lane >> 4, l16 = lane & 15;
  const unsigned char* pA = A8 + (size_t)(bm >> 1) * 131072 +
                            ((bm & 1) * 4) * 2048 + g * 512 + l16 * 32;
  const unsigned char* pB = W8 + (size_t)(bn >> 1) * 131072 +
                            ((bn & 1) * 4) * 2048 + g * 512 + l16 * 32;
  f32x4 acc[4][4];
#pragma unroll
  for (int i = 0; i < 4; ++i)
#pragma unroll
    for (int j = 0; j < 4; ++j) acc[i][j] = (f32x4){0.f, 0.f, 0.f, 0.f};

#pragma unroll 1
  for (int t = 0; t < 8; ++t) {
    i32x8 bF[4];
#pragma unroll
    for (int ni = 0; ni < 4; ++ni)
      bF[ni] = *(const i32x8*)(pB + t * 16384 + ni * 2048);
#pragma unroll
    for (int mi = 0; mi < 4; ++mi) {
      i32x8 aF = *(const i32x8*)(pA + t * 16384 + mi * 2048);
#pragma unroll
      for (int ni = 0; ni < 4; ++ni)
        acc[mi][ni] = __builtin_amdgcn_mfma_scale_f32_16x16x128_f8f6f4(
            aF, bF[ni], acc[mi][ni], 0, 0,
            0, 0x7F7F7F7F, 0, 0x79797979);   // 2^-6 compensates W x64
    }
  }
  int grow0 = bm * 64;
  int gcol0 = bn * 64;
#pragma unroll
  for (int mi = 0; mi < 4; ++mi)
#pragma unroll
    for (int ni = 0; ni < 4; ++ni)
#pragma unroll
      for (int reg = 0; reg < 4; ++reg) {
        int grow = grow0 + mi * 16 + g * 4 + reg;
        int gcol = gcol0 + ni * 16 + l16;
        v[(size_t)grow * 512 + gcol] = __float2bfloat16(acc[mi][ni][reg] + bvec[gcol]);
      }
}

// -- row L2-normalize (v bf16) -> z fp8 fragment-image; 1 wave per row --
__global__ __launch_bounds__(256) void normalize_rows(
    const __hip_bfloat16* __restrict__ v, unsigned char* __restrict__ z) {
  int tid = threadIdx.x;
  int lane = tid & 63;
  int r = blockIdx.x * 4 + (tid >> 6);
  uint4 vv = *(const uint4*)(v + (size_t)r * 512 + lane * 8);
  float x[8];
  unsigned int uu[4] = {vv.x, vv.y, vv.z, vv.w};
#pragma unroll
  for (int q = 0; q < 4; ++q) {
    x[2 * q]     = __uint_as_float(uu[q] << 16);
    x[2 * q + 1] = __uint_as_float(uu[q] & 0xFFFF0000u);
  }
  float s = 0.f;
#pragma unroll
  for (int q = 0; q < 8; ++q) s += x[q] * x[q];
#pragma unroll
  for (int m = 1; m < 64; m <<= 1) s += __shfl_xor(s, m);
  float inv = 1.0f / fmaxf(sqrtf(s), 1e-12f);
  int pk0 = __builtin_amdgcn_cvt_pk_fp8_f32(x[0] * inv, x[1] * inv, 0, 0);
  pk0     = __builtin_amdgcn_cvt_pk_fp8_f32(x[2] * inv, x[3] * inv, pk0, 1);
  int pk1 = __builtin_amdgcn_cvt_pk_fp8_f32(x[4] * inv, x[5] * inv, 0, 0);
  pk1     = __builtin_amdgcn_cvt_pk_fp8_f32(x[6] * inv, x[7] * inv, pk1, 1);
  int k0 = lane * 8;
  size_t off = (size_t)(r >> 7) * 65536 + (size_t)(k0 >> 7) * 16384 +
               (size_t)(((r >> 4) & 7) * 2048 + ((k0 >> 5) & 3) * 512 +
                        (r & 15) * 32 + (k0 & 31));
  uint2 o = {(unsigned int)pk0, (unsigned int)pk1};
  *(uint2*)(z + off) = o;
}

// ==== fused symmetric sim: 1-WAVE blocks, 64x64 tiles, no barriers/LDS ====
// Main loop byte-identical structure to verified R10 (no spill, VGPR 64).
// 192 tiles of 64 rows; bi<=bj; supertile(24)-major, XCD-chunked (8*2316).
__global__ __launch_bounds__(64) void sim_fused_fp8(
    const unsigned char* __restrict__ z, float* __restrict__ partial,
    float* __restrict__ possim, float* __restrict__ selfsim) {
  int l = blockIdx.x;
  int q = (l & 7) * 2316 + (l >> 3);
  int si = 0, sj = 0, jj = q;
  for (;;) {
    int cnt = (si == sj) ? 300 : 576;
    if (jj < cnt) break;
    jj -= cnt;
    ++sj;
    if (sj == 8) { ++si; sj = si; }
  }
  int bi, bj;
  if (si == sj) {
    int rr = 0;
    while (jj >= 24 - rr) { jj -= 24 - rr; ++rr; }
    bi = si * 24 + rr; bj = si * 24 + rr + jj;
  } else {
    bi = si * 24 + jj / 24; bj = sj * 24 + jj % 24;
  }

  int lane = threadIdx.x & 63;
  int g = lane >> 4, l16 = lane & 15;

  // z fragment-image: panel (r>>7)*65536 + ktile*16384 + rowgrp*2048 + ...
  const unsigned char* pA = z + (size_t)(bi >> 1) * 65536 +
                            ((bi & 1) * 4) * 2048 + g * 512 + l16 * 32;
  const unsigned char* pB = z + (size_t)(bj >> 1) * 65536 +
                            ((bj & 1) * 4) * 2048 + g * 512 + l16 * 32;

  f32x4 acc[4][4];
#pragma unroll
  for (int i = 0; i < 4; ++i)
#pragma unroll
    for (int j = 0; j < 4; ++j) acc[i][j] = (f32x4){0.f, 0.f, 0.f, 0.f};

#pragma unroll 1
  for (int t = 0; t < 4; ++t) {
    i32x8 bF[4];
#pragma unroll
    for (int ni = 0; ni < 4; ++ni)
      bF[ni] = *(const i32x8*)(pB + t * 16384 + ni * 2048);
#pragma unroll
    for (int mi = 0; mi < 4; ++mi) {
      i32x8 aF = *(const i32x8*)(pA + t * 16384 + mi * 2048);
#pragma unroll
      for (int ni = 0; ni < 4; ++ni)
        acc[mi][ni] = __builtin_amdgcn_mfma_scale_f32_16x16x128_f8f6f4(
            aF, bF[ni], acc[mi][ni], 0, 0,
            0, 0x7F7F7F7F, 0, 0x7F7F7F7F);
    }
  }

  // --- epilogue: all in-wave, direct partial writes ---
  bool diag = (bi == bj);
  bool posT = (bj == bi + 96);
  if (diag || posT) {
#pragma unroll
    for (int mi = 0; mi < 4; ++mi)
#pragma unroll
      for (int reg = 0; reg < 4; ++reg)
        if (l16 == g * 4 + reg) {
          int rl = mi * 16 + g * 4 + reg;
          float sv = acc[mi][mi][reg];
          if (diag) selfsim[bi * 64 + rl] = sv;
          else      possim[bi * 64 + rl] = sv;   // bi < 96 here
        }
  }
  // exp in place
#pragma unroll
  for (int mi = 0; mi < 4; ++mi)
#pragma unroll
    for (int ni = 0; ni < 4; ++ni)
#pragma unroll
      for (int reg = 0; reg < 4; ++reg)
        acc[mi][ni][reg] = exp2f(acc[mi][ni][reg] * EXP_SCALE);
  // row sums (bi rows): in-thread over ni, l16 shuffle reduce
  float rs[4][4];
#pragma unroll
  for (int mi = 0; mi < 4; ++mi)
#pragma unroll
    for (int reg = 0; reg < 4; ++reg)
      rs[mi][reg] = acc[mi][0][reg] + acc[mi][1][reg] + acc[mi][2][reg] + acc[mi][3][reg];
#pragma unroll
  for (int m = 1; m < 16; m <<= 1)
#pragma unroll
    for (int mi = 0; mi < 4; ++mi)
#pragma unroll
      for (int reg = 0; reg < 4; ++reg)
        rs[mi][reg] += __shfl_xor(rs[mi][reg], m);
  if (l16 == 0) {
#pragma unroll
    for (int mi = 0; mi < 4; ++mi)
#pragma unroll
      for (int reg = 0; reg < 4; ++reg)
        partial[(size_t)bj * NROWS + bi * 64 + mi * 16 + g * 4 + reg] = rs[mi][reg];
  }
  // col sums (bj rows): in-thread over mi,reg, g shuffle reduce
  if (!diag) {
    float cs[4];
#pragma unroll
    for (int ni = 0; ni < 4; ++ni) {
      float s = 0.f;
#pragma unroll
      for (int mi = 0; mi < 4; ++mi)
#pragma unroll
        for (int reg = 0; reg < 4; ++reg) s += acc[mi][ni][reg];
      s += __shfl_xor(s, 16);
      s += __shfl_xor(s, 32);
      cs[ni] = s;
    }
    if (g == 0) {
#pragma unroll
      for (int ni = 0; ni < 4; ++ni)
        partial[(size_t)bi * NROWS + bj * 64 + ni * 16 + l16] = cs[ni];
    }
  }
}

// ---------------- per-row term -> per-block sums (48 floats) ----------
__global__ __launch_bounds__(256) void finalize_terms(
    const float* __restrict__ partial, const float* __restrict__ possim,
    const float* __restrict__ selfsim, float* __restrict__ blocksum) {
  int i = blockIdx.x * 256 + threadIdx.x;
  float s = 0.f;
  for (int bjt = 0; bjt < NT64; ++bjt) s += partial[(size_t)bjt * NROWS + i];
  float denom = s - exp2f(selfsim[i] * EXP_SCALE);
  float pos = possim[(i < HALF) ? i : (i - HALF)];
  float term = -2.0f * pos + logf(denom);
#pragma unroll
  for (int m = 1; m < 64; m <<= 1) term += __shfl_xor(term, m);
  __shared__ float ws4[4];
  int tid = threadIdx.x, w = tid >> 6, lane = tid & 63;
  if (lane == 0) ws4[w] = term;
  __syncthreads();
  if (tid == 0) blocksum[blockIdx.x] = ws4[0] + ws4[1] + ws4[2] + ws4[3];
}

// ---------------- final reduce: 48 values, one wave ----------------
__global__ __launch_bounds__(64) void finalize_sum(
    const float* __restrict__ blocksum, float* __restrict__ out) {
  int tid = threadIdx.x;
  float s = (tid < 48) ? blocksum[tid] : 0.f;
#pragma unroll
  for (int m = 1; m < 64; m <<= 1) s += __shfl_xor(s, m);
  if (tid == 0) out[0] = s / 12288.0f;
}

extern "C" void kernel_launch(void* const* d_in, const int* in_sizes, int n_in,
                              void* d_out, int out_size, void* d_ws, size_t ws_size,
                              hipStream_t stream) {
  const float* f_seq = (const float*)d_in[0];
  const float* f_spa = (const float*)d_in[1];
  const float* W     = (const float*)d_in[2];
  const float* b     = (const float*)d_in[3];
  char* ws = (char*)d_ws;
  unsigned char* A8  = (unsigned char*)ws;                   // 12,582,912 B
  unsigned char* z   = (unsigned char*)ws;                   // 6,291,456 B (aliases dead A8)
  float* partial     = (float*)(ws + 12582912);              // 192*12288*4 = 9,437,184
  unsigned char* W8  = (unsigned char*)(ws + 22020096);      // 524,288 B
  float* possim      = (float*)(ws + 22544384);              // 6144*4
  float* selfsim     = (float*)(ws + 22568960);              // 12288*4
  float* blocksum    = (float*)(ws + 22618112);              // 48*4
  __hip_bfloat16* v  = (__hip_bfloat16*)(ws + 26214400);     // 12,582,912 B
  float* out         = (float*)d_out;

  gather_fp8<<<dim3(1600), dim3(256), 0, stream>>>(f_seq, f_spa, W, A8, W8);
  proj_fp8<<<dim3(8, 192), dim3(64), 0, stream>>>(A8, W8, b, v);
  normalize_rows<<<dim3(3072), dim3(256), 0, stream>>>(v, z);
  sim_fused_fp8<<<dim3(NPAIR64), dim3(64), 0, stream>>>(z, partial, possim, selfsim);
  finalize_terms<<<dim3(48), dim3(256), 0, stream>>>(partial, possim, selfsim, blocksum);
  finalize_sum<<<dim3(1), dim3(64), 0, stream>>>(blocksum, out);
}

// Round 18
// 101.826 us; speedup vs baseline: 1.1292x; 1.1292x over previous
//
#include <hip/hip_runtime.h>
#include <hip/hip_bf16.h>
#include <cstdint>
#include <cstddef>

#define B_DIM 2048
#define D_DIM 512
#define NROWS 12288        // 6B rows of z
#define HALF  6144         // 3B
#define NTILE 96           // 128-row tiles per dim
#define NPAIR 4656         // 96*97/2 upper-tri tiles
#define EXP_SCALE 2.8853900817779268f   // log2(e)/TEMP, TEMP=0.5

typedef __attribute__((ext_vector_type(4))) float f32x4;
typedef __attribute__((ext_vector_type(8))) int i32x8;

// ---- merged gather: f -> A8 fp8 fragment-image (16x16 map), W*64 -> W8 ----
// off(r,k) = (r>>7)*131072 + (k>>7)*16384 + ((r>>4)&7)*2048
//            + ((k>>5)&3)*512 + (r&15)*32 + (k&31)
__global__ __launch_bounds__(256) void gather_fp8(
    const float* __restrict__ f_seq, const float* __restrict__ f_spa,
    const float* __restrict__ W,
    unsigned char* __restrict__ A8, unsigned char* __restrict__ W8) {
  int gidx = blockIdx.x * 256 + threadIdx.x;
  if (blockIdx.x < 1536) {
    int r = gidx >> 5;          // row 0..12287
    int c = gidx & 31;          // 32-elem k-chunk
    int k0 = c << 5;
    const float* f = (r < HALF) ? f_spa : f_seq;
    int rr = (r < HALF) ? r : r - HALF;
    int p = rr >> 11;
    int i = rr & 2047;
    int sel = (p == 2) ? 3 : p;
    const float* src = (k0 < D_DIM) ? f + ((size_t)i * 4 + sel) * D_DIM + k0
                                    : f + ((size_t)i * 4 + 2) * D_DIM + (k0 - D_DIM);
    unsigned int d[8];
#pragma unroll
    for (int q = 0; q < 8; ++q) {
      float4 x = *(const float4*)(src + 4 * q);
      int pk = __builtin_amdgcn_cvt_pk_fp8_f32(x.x, x.y, 0, 0);
      pk     = __builtin_amdgcn_cvt_pk_fp8_f32(x.z, x.w, pk, 1);
      d[q] = (unsigned int)pk;
    }
    size_t off = (size_t)(r >> 7) * 131072 + (size_t)(c >> 2) * 16384 +
                 (size_t)(((r >> 4) & 7) * 2048 + (c & 3) * 512 + (r & 15) * 32);
    *(uint4*)(A8 + off)      = (uint4){d[0], d[1], d[2], d[3]};
    *(uint4*)(A8 + off + 16) = (uint4){d[4], d[5], d[6], d[7]};
  } else {
    int widx = gidx - 1536 * 256;   // 0..16383
    int n = widx >> 5;              // 0..511
    int c = widx & 31;
    int k0 = c << 5;
    unsigned int d[8];
#pragma unroll
    for (int q = 0; q < 8; ++q) {
      float a0 = W[(size_t)(k0 + 4 * q + 0) * 512 + n] * 64.0f;
      float a1 = W[(size_t)(k0 + 4 * q + 1) * 512 + n] * 64.0f;
      float a2 = W[(size_t)(k0 + 4 * q + 2) * 512 + n] * 64.0f;
      float a3 = W[(size_t)(k0 + 4 * q + 3) * 512 + n] * 64.0f;
      int pk = __builtin_amdgcn_cvt_pk_fp8_f32(a0, a1, 0, 0);
      pk     = __builtin_amdgcn_cvt_pk_fp8_f32(a2, a3, pk, 1);
      d[q] = (unsigned int)pk;
    }
    size_t off = (size_t)(n >> 7) * 131072 + (size_t)(c >> 2) * 16384 +
                 (size_t)(((n >> 4) & 7) * 2048 + (c & 3) * 512 + (n & 15) * 32);
    *(uint4*)(W8 + off)      = (uint4){d[0], d[1], d[2], d[3]};
    *(uint4*)(W8 + off + 16) = (uint4){d[4], d[5], d[6], d[7]};
  }
}

// ---- projection GEMM fp8 MX: sim-shaped (128x128 tile, 64x64 wave tile) ----
// v = A @ W^T * 2^-6 + b (bf16 out). Grid (4, 96), block 256.
__global__ __launch_bounds__(256, 4) void proj_fp8(
    const unsigned char* __restrict__ A8, const unsigned char* __restrict__ W8,
    const float* __restrict__ bvec, __hip_bfloat16* __restrict__ v) {
  int bn = blockIdx.x;        // 0..3   (128-col group)
  int bm = blockIdx.y;        // 0..95  (128-row tile)
  int tid = threadIdx.x;
  int lane = tid & 63;
  int w = tid >> 6, wr = w >> 1, wc = w & 1;
  int g = lane >> 4, l16 = lane & 15;
  const unsigned char* pA = A8 + (size_t)bm * 131072 + (wr * 4) * 2048 + g * 512 + l16 * 32;
  const unsigned char* pB = W8 + (size_t)bn * 131072 + (wc * 4) * 2048 + g * 512 + l16 * 32;
  f32x4 acc[4][4];
#pragma unroll
  for (int i = 0; i < 4; ++i)
#pragma unroll
    for (int j = 0; j < 4; ++j) acc[i][j] = (f32x4){0.f, 0.f, 0.f, 0.f};

#pragma unroll 1
  for (int t = 0; t < 8; ++t) {
    i32x8 bF[4];
#pragma unroll
    for (int ni = 0; ni < 4; ++ni)
      bF[ni] = *(const i32x8*)(pB + t * 16384 + ni * 2048);
#pragma unroll
    for (int mi = 0; mi < 4; ++mi) {
      i32x8 aF = *(const i32x8*)(pA + t * 16384 + mi * 2048);
#pragma unroll
      for (int ni = 0; ni < 4; ++ni)
        acc[mi][ni] = __builtin_amdgcn_mfma_scale_f32_16x16x128_f8f6f4(
            aF, bF[ni], acc[mi][ni], 0, 0,
            0, 0x7F7F7F7F, 0, 0x79797979);   // 2^-6 compensates W x64
    }
  }
  int grow0 = bm * 128 + wr * 64;
  int gcol0 = bn * 128 + wc * 64;
#pragma unroll
  for (int mi = 0; mi < 4; ++mi)
#pragma unroll
    for (int ni = 0; ni < 4; ++ni)
#pragma unroll
      for (int reg = 0; reg < 4; ++reg) {
        int grow = grow0 + mi * 16 + g * 4 + reg;
        int gcol = gcol0 + ni * 16 + l16;
        v[(size_t)grow * 512 + gcol] = __float2bfloat16(acc[mi][ni][reg] + bvec[gcol]);
      }
}

// -- row L2-normalize (v bf16) -> z fp8 fragment-image; 1 wave per row --
__global__ __launch_bounds__(256) void normalize_rows(
    const __hip_bfloat16* __restrict__ v, unsigned char* __restrict__ z) {
  int tid = threadIdx.x;
  int lane = tid & 63;
  int r = blockIdx.x * 4 + (tid >> 6);
  uint4 vv = *(const uint4*)(v + (size_t)r * 512 + lane * 8);
  float x[8];
  unsigned int uu[4] = {vv.x, vv.y, vv.z, vv.w};
#pragma unroll
  for (int q = 0; q < 4; ++q) {
    x[2 * q]     = __uint_as_float(uu[q] << 16);
    x[2 * q + 1] = __uint_as_float(uu[q] & 0xFFFF0000u);
  }
  float s = 0.f;
#pragma unroll
  for (int q = 0; q < 8; ++q) s += x[q] * x[q];
#pragma unroll
  for (int m = 1; m < 64; m <<= 1) s += __shfl_xor(s, m);
  float inv = 1.0f / fmaxf(sqrtf(s), 1e-12f);
  int pk0 = __builtin_amdgcn_cvt_pk_fp8_f32(x[0] * inv, x[1] * inv, 0, 0);
  pk0     = __builtin_amdgcn_cvt_pk_fp8_f32(x[2] * inv, x[3] * inv, pk0, 1);
  int pk1 = __builtin_amdgcn_cvt_pk_fp8_f32(x[4] * inv, x[5] * inv, 0, 0);
  pk1     = __builtin_amdgcn_cvt_pk_fp8_f32(x[6] * inv, x[7] * inv, pk1, 1);
  int k0 = lane * 8;
  size_t off = (size_t)(r >> 7) * 65536 + (size_t)(k0 >> 7) * 16384 +
               (size_t)(((r >> 4) & 7) * 2048 + ((k0 >> 5) & 3) * 512 +
                        (r & 15) * 32 + (k0 & 31));
  uint2 o = {(unsigned int)pk0, (unsigned int)pk1};
  *(uint2*)(z + off) = o;
}

// ==== fused symmetric sim, fp8 MX: verified R10/R15 loop (64.7us, no spill) ====
__global__ __launch_bounds__(256, 4) void sim_fused_fp8(
    const unsigned char* __restrict__ z, float* __restrict__ partial,
    float* __restrict__ possim, float* __restrict__ selfsim) {
  __shared__ float wsum[2][128];
  __shared__ float csum[2][128];

  // --- block -> (bi,bj), bi<=bj<96, supertile(12x12)-major, XCD-chunked ---
  int l = blockIdx.x;
  int q = (l & 7) * 582 + (l >> 3);
  int si = 0, sj = 0, jj = q;
  for (;;) {
    int cnt = (si == sj) ? 78 : 144;
    if (jj < cnt) break;
    jj -= cnt;
    ++sj;
    if (sj == 8) { ++si; sj = si; }
  }
  int bi, bj;
  if (si == sj) {
    int rr = 0;
    while (jj >= 12 - rr) { jj -= 12 - rr; ++rr; }
    bi = si * 12 + rr; bj = si * 12 + rr + jj;
  } else {
    bi = si * 12 + jj / 12; bj = sj * 12 + jj % 12;
  }

  int tid = threadIdx.x;
  int lane = tid & 63;
  int w = tid >> 6, wr = w >> 1, wc = w & 1;
  int g = lane >> 4, l16 = lane & 15;

  const unsigned char* pA = z + (size_t)bi * 65536 + (size_t)(wr * 4) * 2048 + g * 512 + l16 * 32;
  const unsigned char* pB = z + (size_t)bj * 65536 + (size_t)(wc * 4) * 2048 + g * 512 + l16 * 32;

  f32x4 acc[4][4];
#pragma unroll
  for (int i = 0; i < 4; ++i)
#pragma unroll
    for (int j = 0; j < 4; ++j) acc[i][j] = (f32x4){0.f, 0.f, 0.f, 0.f};

#pragma unroll 1
  for (int t = 0; t < 4; ++t) {
    i32x8 bF[4];
#pragma unroll
    for (int ni = 0; ni < 4; ++ni)
      bF[ni] = *(const i32x8*)(pB + t * 16384 + ni * 2048);
#pragma unroll
    for (int mi = 0; mi < 4; ++mi) {
      i32x8 aF = *(const i32x8*)(pA + t * 16384 + mi * 2048);
#pragma unroll
      for (int ni = 0; ni < 4; ++ni)
        acc[mi][ni] = __builtin_amdgcn_mfma_scale_f32_16x16x128_f8f6f4(
            aF, bF[ni], acc[mi][ni], 0, 0,
            0, 0x7F7F7F7F, 0, 0x7F7F7F7F);
    }
  }

  // --- epilogue (identical to verified R5-R15 version) ---
  bool diag = (bi == bj);
  bool posT = (bj == bi + 48);
  if ((diag || posT) && (wr == wc)) {
#pragma unroll
    for (int mi = 0; mi < 4; ++mi)
#pragma unroll
      for (int reg = 0; reg < 4; ++reg)
        if (l16 == g * 4 + reg) {
          int rl = wr * 64 + mi * 16 + g * 4 + reg;
          float sv = acc[mi][mi][reg];
          if (diag) selfsim[bi * 128 + rl] = sv;
          else      possim[bi * 128 + rl] = sv;   // bi < 48 here
        }
  }
  // exp in place
#pragma unroll
  for (int mi = 0; mi < 4; ++mi)
#pragma unroll
    for (int ni = 0; ni < 4; ++ni)
#pragma unroll
      for (int reg = 0; reg < 4; ++reg)
        acc[mi][ni][reg] = exp2f(acc[mi][ni][reg] * EXP_SCALE);
  // row sums (bi rows): in-thread over ni, l16 shuffle reduce
  float rs[4][4];
#pragma unroll
  for (int mi = 0; mi < 4; ++mi)
#pragma unroll
    for (int reg = 0; reg < 4; ++reg)
      rs[mi][reg] = acc[mi][0][reg] + acc[mi][1][reg] + acc[mi][2][reg] + acc[mi][3][reg];
#pragma unroll
  for (int m = 1; m < 16; m <<= 1)
#pragma unroll
    for (int mi = 0; mi < 4; ++mi)
#pragma unroll
      for (int reg = 0; reg < 4; ++reg)
        rs[mi][reg] += __shfl_xor(rs[mi][reg], m);
  if (l16 == 0) {
#pragma unroll
    for (int mi = 0; mi < 4; ++mi)
#pragma unroll
      for (int reg = 0; reg < 4; ++reg)
        wsum[wc][wr * 64 + mi * 16 + g * 4 + reg] = rs[mi][reg];
  }
  // col sums (bj rows): in-thread over mi,reg, g shuffle reduce
  float cs[4];
#pragma unroll
  for (int ni = 0; ni < 4; ++ni) {
    float s = 0.f;
#pragma unroll
    for (int mi = 0; mi < 4; ++mi)
#pragma unroll
      for (int reg = 0; reg < 4; ++reg) s += acc[mi][ni][reg];
    s += __shfl_xor(s, 16);
    s += __shfl_xor(s, 32);
    cs[ni] = s;
  }
  if (g == 0) {
#pragma unroll
    for (int ni = 0; ni < 4; ++ni)
      csum[wr][wc * 64 + ni * 16 + l16] = cs[ni];
  }
  __syncthreads();
  if (tid < 128) {
    partial[(size_t)bj * NROWS + bi * 128 + tid] = wsum[0][tid] + wsum[1][tid];
    if (!diag)
      partial[(size_t)bi * NROWS + bj * 128 + tid] = csum[0][tid] + csum[1][tid];
  }
}

// ---------------- per-row term -> per-block sums (48 floats) ----------
__global__ __launch_bounds__(256) void finalize_terms(
    const float* __restrict__ partial, const float* __restrict__ possim,
    const float* __restrict__ selfsim, float* __restrict__ blocksum) {
  int i = blockIdx.x * 256 + threadIdx.x;
  float s = 0.f;
  for (int bjt = 0; bjt < NTILE; ++bjt) s += partial[(size_t)bjt * NROWS + i];
  float denom = s - exp2f(selfsim[i] * EXP_SCALE);
  float pos = possim[(i < HALF) ? i : (i - HALF)];
  float term = -2.0f * pos + logf(denom);
#pragma unroll
  for (int m = 1; m < 64; m <<= 1) term += __shfl_xor(term, m);
  __shared__ float ws4[4];
  int tid = threadIdx.x, w = tid >> 6, lane = tid & 63;
  if (lane == 0) ws4[w] = term;
  __syncthreads();
  if (tid == 0) blocksum[blockIdx.x] = ws4[0] + ws4[1] + ws4[2] + ws4[3];
}

// ---------------- final reduce: 48 values, one wave ----------------
__global__ __launch_bounds__(64) void finalize_sum(
    const float* __restrict__ blocksum, float* __restrict__ out) {
  int tid = threadIdx.x;
  float s = (tid < 48) ? blocksum[tid] : 0.f;
#pragma unroll
  for (int m = 1; m < 64; m <<= 1) s += __shfl_xor(s, m);
  if (tid == 0) out[0] = s / 12288.0f;
}

extern "C" void kernel_launch(void* const* d_in, const int* in_sizes, int n_in,
                              void* d_out, int out_size, void* d_ws, size_t ws_size,
                              hipStream_t stream) {
  const float* f_seq = (const float*)d_in[0];
  const float* f_spa = (const float*)d_in[1];
  const float* W     = (const float*)d_in[2];
  const float* b     = (const float*)d_in[3];
  char* ws = (char*)d_ws;
  unsigned char* A8  = (unsigned char*)ws;                   // 12,582,912 B
  unsigned char* W8  = (unsigned char*)(ws + 12582912);      // 524,288 B (dead after proj)
  __hip_bfloat16* v  = (__hip_bfloat16*)(ws + 26214400);     // 12,582,912 B
  unsigned char* z   = (unsigned char*)ws;                   // 6,291,456 B (aliases dead A8)
  float* partial     = (float*)(ws + 12582912);              // 4,718,592 B (aliases dead W8)
  float* possim      = (float*)(ws + 17301504);              // 6144*4
  float* selfsim     = (float*)(ws + 17326080);              // 12288*4
  float* blocksum    = (float*)(ws + 17375232);              // 48*4
  float* out         = (float*)d_out;

  gather_fp8<<<dim3(1600), dim3(256), 0, stream>>>(f_seq, f_spa, W, A8, W8);
  proj_fp8<<<dim3(4, 96), dim3(256), 0, stream>>>(A8, W8, b, v);
  normalize_rows<<<dim3(3072), dim3(256), 0, stream>>>(v, z);
  sim_fused_fp8<<<dim3(NPAIR), dim3(256), 0, stream>>>(z, partial, possim, selfsim);
  finalize_terms<<<dim3(48), dim3(256), 0, stream>>>(partial, possim, selfsim, blocksum);
  finalize_sum<<<dim3(1), dim3(64), 0, stream>>>(blocksum, out);
}

// Round 19
// 88.987 us; speedup vs baseline: 1.2921x; 1.1443x over previous
//
#include <hip/hip_runtime.h>
#include <hip/hip_bf16.h>
#include <cstdint>
#include <cstddef>

#define B_DIM 2048
#define D_DIM 512
#define NROWS 12288        // 6B rows of z
#define HALF  6144         // 3B
#define NTILE 96           // 128-row tiles per dim
#define NPAIR 4656         // 96*97/2 upper-tri tiles
#define EXP_SCALE 2.8853900817779268f   // log2(e)/TEMP, TEMP=0.5

typedef __attribute__((ext_vector_type(4))) float f32x4;
typedef __attribute__((ext_vector_type(8))) int i32x8;

// ---- merged gather: f -> A8 fp8 fragment-image (16x16 map), W*64 -> W8 ----
// off(r,k) = (r>>7)*131072 + (k>>7)*16384 + ((r>>4)&7)*2048
//            + ((k>>5)&3)*512 + (r&15)*32 + (k&31)
__global__ __launch_bounds__(256) void gather_fp8(
    const float* __restrict__ f_seq, const float* __restrict__ f_spa,
    const float* __restrict__ W,
    unsigned char* __restrict__ A8, unsigned char* __restrict__ W8) {
  int gidx = blockIdx.x * 256 + threadIdx.x;
  if (blockIdx.x < 1536) {
    int r = gidx >> 5;          // row 0..12287
    int c = gidx & 31;          // 32-elem k-chunk
    int k0 = c << 5;
    const float* f = (r < HALF) ? f_spa : f_seq;
    int rr = (r < HALF) ? r : r - HALF;
    int p = rr >> 11;
    int i = rr & 2047;
    int sel = (p == 2) ? 3 : p;
    const float* src = (k0 < D_DIM) ? f + ((size_t)i * 4 + sel) * D_DIM + k0
                                    : f + ((size_t)i * 4 + 2) * D_DIM + (k0 - D_DIM);
    unsigned int d[8];
#pragma unroll
    for (int q = 0; q < 8; ++q) {
      float4 x = *(const float4*)(src + 4 * q);
      int pk = __builtin_amdgcn_cvt_pk_fp8_f32(x.x, x.y, 0, 0);
      pk     = __builtin_amdgcn_cvt_pk_fp8_f32(x.z, x.w, pk, 1);
      d[q] = (unsigned int)pk;
    }
    size_t off = (size_t)(r >> 7) * 131072 + (size_t)(c >> 2) * 16384 +
                 (size_t)(((r >> 4) & 7) * 2048 + (c & 3) * 512 + (r & 15) * 32);
    *(uint4*)(A8 + off)      = (uint4){d[0], d[1], d[2], d[3]};
    *(uint4*)(A8 + off + 16) = (uint4){d[4], d[5], d[6], d[7]};
  } else {
    int widx = gidx - 1536 * 256;   // 0..16383
    int n = widx >> 5;              // 0..511
    int c = widx & 31;
    int k0 = c << 5;
    unsigned int d[8];
#pragma unroll
    for (int q = 0; q < 8; ++q) {
      float a0 = W[(size_t)(k0 + 4 * q + 0) * 512 + n] * 64.0f;
      float a1 = W[(size_t)(k0 + 4 * q + 1) * 512 + n] * 64.0f;
      float a2 = W[(size_t)(k0 + 4 * q + 2) * 512 + n] * 64.0f;
      float a3 = W[(size_t)(k0 + 4 * q + 3) * 512 + n] * 64.0f;
      int pk = __builtin_amdgcn_cvt_pk_fp8_f32(a0, a1, 0, 0);
      pk     = __builtin_amdgcn_cvt_pk_fp8_f32(a2, a3, pk, 1);
      d[q] = (unsigned int)pk;
    }
    size_t off = (size_t)(n >> 7) * 131072 + (size_t)(c >> 2) * 16384 +
                 (size_t)(((n >> 4) & 7) * 2048 + (c & 3) * 512 + (n & 15) * 32);
    *(uint4*)(W8 + off)      = (uint4){d[0], d[1], d[2], d[3]};
    *(uint4*)(W8 + off + 16) = (uint4){d[4], d[5], d[6], d[7]};
  }
}

// ---- projection GEMM fp8 MX: sim-shaped (128x128 tile, 64x64 wave tile) ----
// v = A @ W^T * 2^-6 + b (bf16 out). Grid (4, 96), block 256.
__global__ __launch_bounds__(256, 4) void proj_fp8(
    const unsigned char* __restrict__ A8, const unsigned char* __restrict__ W8,
    const float* __restrict__ bvec, __hip_bfloat16* __restrict__ v) {
  int bn = blockIdx.x;        // 0..3   (128-col group)
  int bm = blockIdx.y;        // 0..95  (128-row tile)
  int tid = threadIdx.x;
  int lane = tid & 63;
  int w = tid >> 6, wr = w >> 1, wc = w & 1;
  int g = lane >> 4, l16 = lane & 15;
  const unsigned char* pA = A8 + (size_t)bm * 131072 + (wr * 4) * 2048 + g * 512 + l16 * 32;
  const unsigned char* pB = W8 + (size_t)bn * 131072 + (wc * 4) * 2048 + g * 512 + l16 * 32;
  f32x4 acc[4][4];
#pragma unroll
  for (int i = 0; i < 4; ++i)
#pragma unroll
    for (int j = 0; j < 4; ++j) acc[i][j] = (f32x4){0.f, 0.f, 0.f, 0.f};

#pragma unroll 1
  for (int t = 0; t < 8; ++t) {
    i32x8 bF[4];
#pragma unroll
    for (int ni = 0; ni < 4; ++ni)
      bF[ni] = *(const i32x8*)(pB + t * 16384 + ni * 2048);
#pragma unroll
    for (int mi = 0; mi < 4; ++mi) {
      i32x8 aF = *(const i32x8*)(pA + t * 16384 + mi * 2048);
#pragma unroll
      for (int ni = 0; ni < 4; ++ni)
        acc[mi][ni] = __builtin_amdgcn_mfma_scale_f32_16x16x128_f8f6f4(
            aF, bF[ni], acc[mi][ni], 0, 0,
            0, 0x7F7F7F7F, 0, 0x79797979);   // 2^-6 compensates W x64
    }
  }
  int grow0 = bm * 128 + wr * 64;
  int gcol0 = bn * 128 + wc * 64;
#pragma unroll
  for (int mi = 0; mi < 4; ++mi)
#pragma unroll
    for (int ni = 0; ni < 4; ++ni)
#pragma unroll
      for (int reg = 0; reg < 4; ++reg) {
        int grow = grow0 + mi * 16 + g * 4 + reg;
        int gcol = gcol0 + ni * 16 + l16;
        v[(size_t)grow * 512 + gcol] = __float2bfloat16(acc[mi][ni][reg] + bvec[gcol]);
      }
}

// -- row L2-normalize (v bf16) -> z fp4(e2m1) fragment-image; 1 wave/row --
// Fixed MX scale 2^-4 (byte 0x7B); codes = z*16 rounded to e2m1 grid.
// off4(r,k) = (r>>7)*32768 + (k>>7)*8192 + ((r>>4)&7)*1024
//             + ((k>>5)&3)*256 + (r&15)*16 + ((k&31)>>1)
__global__ __launch_bounds__(256) void normalize_rows(
    const __hip_bfloat16* __restrict__ v, unsigned char* __restrict__ z4) {
  int tid = threadIdx.x;
  int lane = tid & 63;
  int r = blockIdx.x * 4 + (tid >> 6);
  uint4 vv = *(const uint4*)(v + (size_t)r * 512 + lane * 8);
  float x[8];
  unsigned int uu[4] = {vv.x, vv.y, vv.z, vv.w};
#pragma unroll
  for (int q = 0; q < 4; ++q) {
    x[2 * q]     = __uint_as_float(uu[q] << 16);
    x[2 * q + 1] = __uint_as_float(uu[q] & 0xFFFF0000u);
  }
  float s = 0.f;
#pragma unroll
  for (int q = 0; q < 8; ++q) s += x[q] * x[q];
#pragma unroll
  for (int m = 1; m < 64; m <<= 1) s += __shfl_xor(s, m);
  float inv16 = 16.0f / fmaxf(sqrtf(s), 1e-12f);
  unsigned int nibs = 0;
#pragma unroll
  for (int q = 0; q < 8; ++q) {
    float u = x[q] * inv16;
    float a = fabsf(u);
    unsigned int c = (unsigned int)(a >= 0.25f) + (unsigned int)(a >= 0.75f) +
                     (unsigned int)(a >= 1.25f) + (unsigned int)(a >= 1.75f) +
                     (unsigned int)(a >= 2.5f)  + (unsigned int)(a >= 3.5f) +
                     (unsigned int)(a >= 5.0f);
    c |= (u < 0.f) ? 8u : 0u;
    nibs |= c << (4 * q);
  }
  int k0 = lane * 8;
  size_t off = (size_t)(r >> 7) * 32768 + (size_t)(k0 >> 7) * 8192 +
               (size_t)(((r >> 4) & 7) * 1024 + ((k0 >> 5) & 3) * 256 +
                        (r & 15) * 16 + ((k0 & 31) >> 1));
  *(unsigned int*)(z4 + off) = nibs;
}

// ==== fused symmetric sim, fp4 MX (cbsz=blgp=4): R10-structure loop ====
// Fragment = 16B/lane (single dwordx4 load); upper operand half duplicated.
__global__ __launch_bounds__(256, 4) void sim_fused_fp8(
    const unsigned char* __restrict__ z4, float* __restrict__ partial,
    float* __restrict__ possim, float* __restrict__ selfsim) {
  __shared__ float wsum[2][128];
  __shared__ float csum[2][128];

  // --- block -> (bi,bj), bi<=bj<96, supertile(12x12)-major, XCD-chunked ---
  int l = blockIdx.x;
  int q = (l & 7) * 582 + (l >> 3);
  int si = 0, sj = 0, jj = q;
  for (;;) {
    int cnt = (si == sj) ? 78 : 144;
    if (jj < cnt) break;
    jj -= cnt;
    ++sj;
    if (sj == 8) { ++si; sj = si; }
  }
  int bi, bj;
  if (si == sj) {
    int rr = 0;
    while (jj >= 12 - rr) { jj -= 12 - rr; ++rr; }
    bi = si * 12 + rr; bj = si * 12 + rr + jj;
  } else {
    bi = si * 12 + jj / 12; bj = sj * 12 + jj % 12;
  }

  int tid = threadIdx.x;
  int lane = tid & 63;
  int w = tid >> 6, wr = w >> 1, wc = w & 1;
  int g = lane >> 4, l16 = lane & 15;

  const unsigned char* pA = z4 + (size_t)bi * 32768 + (wr * 4) * 1024 + g * 256 + l16 * 16;
  const unsigned char* pB = z4 + (size_t)bj * 32768 + (wc * 4) * 1024 + g * 256 + l16 * 16;

  f32x4 acc[4][4];
#pragma unroll
  for (int i = 0; i < 4; ++i)
#pragma unroll
    for (int j = 0; j < 4; ++j) acc[i][j] = (f32x4){0.f, 0.f, 0.f, 0.f};

#pragma unroll 1
  for (int t = 0; t < 4; ++t) {
    i32x8 bF[4];
#pragma unroll
    for (int ni = 0; ni < 4; ++ni) {
      uint4 tb = *(const uint4*)(pB + t * 8192 + ni * 1024);
      bF[ni] = (i32x8){(int)tb.x, (int)tb.y, (int)tb.z, (int)tb.w,
                       (int)tb.x, (int)tb.y, (int)tb.z, (int)tb.w};
    }
#pragma unroll
    for (int mi = 0; mi < 4; ++mi) {
      uint4 ta = *(const uint4*)(pA + t * 8192 + mi * 1024);
      i32x8 aF = (i32x8){(int)ta.x, (int)ta.y, (int)ta.z, (int)ta.w,
                         (int)ta.x, (int)ta.y, (int)ta.z, (int)ta.w};
#pragma unroll
      for (int ni = 0; ni < 4; ++ni)
        acc[mi][ni] = __builtin_amdgcn_mfma_scale_f32_16x16x128_f8f6f4(
            aF, bF[ni], acc[mi][ni], 4, 4,
            0, 0x7B7B7B7B, 0, 0x7B7B7B7B);   // fp4 e2m1, scale 2^-4 both
    }
  }

  // --- epilogue (identical to verified R5-R18 version) ---
  bool diag = (bi == bj);
  bool posT = (bj == bi + 48);
  if ((diag || posT) && (wr == wc)) {
#pragma unroll
    for (int mi = 0; mi < 4; ++mi)
#pragma unroll
      for (int reg = 0; reg < 4; ++reg)
        if (l16 == g * 4 + reg) {
          int rl = wr * 64 + mi * 16 + g * 4 + reg;
          float sv = acc[mi][mi][reg];
          if (diag) selfsim[bi * 128 + rl] = sv;
          else      possim[bi * 128 + rl] = sv;   // bi < 48 here
        }
  }
  // exp in place
#pragma unroll
  for (int mi = 0; mi < 4; ++mi)
#pragma unroll
    for (int ni = 0; ni < 4; ++ni)
#pragma unroll
      for (int reg = 0; reg < 4; ++reg)
        acc[mi][ni][reg] = exp2f(acc[mi][ni][reg] * EXP_SCALE);
  // row sums (bi rows): in-thread over ni, l16 shuffle reduce
  float rs[4][4];
#pragma unroll
  for (int mi = 0; mi < 4; ++mi)
#pragma unroll
    for (int reg = 0; reg < 4; ++reg)
      rs[mi][reg] = acc[mi][0][reg] + acc[mi][1][reg] + acc[mi][2][reg] + acc[mi][3][reg];
#pragma unroll
  for (int m = 1; m < 16; m <<= 1)
#pragma unroll
    for (int mi = 0; mi < 4; ++mi)
#pragma unroll
      for (int reg = 0; reg < 4; ++reg)
        rs[mi][reg] += __shfl_xor(rs[mi][reg], m);
  if (l16 == 0) {
#pragma unroll
    for (int mi = 0; mi < 4; ++mi)
#pragma unroll
      for (int reg = 0; reg < 4; ++reg)
        wsum[wc][wr * 64 + mi * 16 + g * 4 + reg] = rs[mi][reg];
  }
  // col sums (bj rows): in-thread over mi,reg, g shuffle reduce
  float cs[4];
#pragma unroll
  for (int ni = 0; ni < 4; ++ni) {
    float s = 0.f;
#pragma unroll
    for (int mi = 0; mi < 4; ++mi)
#pragma unroll
      for (int reg = 0; reg < 4; ++reg) s += acc[mi][ni][reg];
    s += __shfl_xor(s, 16);
    s += __shfl_xor(s, 32);
    cs[ni] = s;
  }
  if (g == 0) {
#pragma unroll
    for (int ni = 0; ni < 4; ++ni)
      csum[wr][wc * 64 + ni * 16 + l16] = cs[ni];
  }
  __syncthreads();
  if (tid < 128) {
    partial[(size_t)bj * NROWS + bi * 128 + tid] = wsum[0][tid] + wsum[1][tid];
    if (!diag)
      partial[(size_t)bi * NROWS + bj * 128 + tid] = csum[0][tid] + csum[1][tid];
  }
}

// ---------------- per-row term -> per-block sums (48 floats) ----------
__global__ __launch_bounds__(256) void finalize_terms(
    const float* __restrict__ partial, const float* __restrict__ possim,
    const float* __restrict__ selfsim, float* __restrict__ blocksum) {
  int i = blockIdx.x * 256 + threadIdx.x;
  float s = 0.f;
  for (int bjt = 0; bjt < NTILE; ++bjt) s += partial[(size_t)bjt * NROWS + i];
  float denom = s - exp2f(selfsim[i] * EXP_SCALE);
  float pos = possim[(i < HALF) ? i : (i - HALF)];
  float term = -2.0f * pos + logf(denom);
#pragma unroll
  for (int m = 1; m < 64; m <<= 1) term += __shfl_xor(term, m);
  __shared__ float ws4[4];
  int tid = threadIdx.x, w = tid >> 6, lane = tid & 63;
  if (lane == 0) ws4[w] = term;
  __syncthreads();
  if (tid == 0) blocksum[blockIdx.x] = ws4[0] + ws4[1] + ws4[2] + ws4[3];
}

// ---------------- final reduce: 48 values, one wave ----------------
__global__ __launch_bounds__(64) void finalize_sum(
    const float* __restrict__ blocksum, float* __restrict__ out) {
  int tid = threadIdx.x;
  float s = (tid < 48) ? blocksum[tid] : 0.f;
#pragma unroll
  for (int m = 1; m < 64; m <<= 1) s += __shfl_xor(s, m);
  if (tid == 0) out[0] = s / 12288.0f;
}

extern "C" void kernel_launch(void* const* d_in, const int* in_sizes, int n_in,
                              void* d_out, int out_size, void* d_ws, size_t ws_size,
                              hipStream_t stream) {
  const float* f_seq = (const float*)d_in[0];
  const float* f_spa = (const float*)d_in[1];
  const float* W     = (const float*)d_in[2];
  const float* b     = (const float*)d_in[3];
  char* ws = (char*)d_ws;
  unsigned char* A8  = (unsigned char*)ws;                   // 12,582,912 B
  unsigned char* W8  = (unsigned char*)(ws + 12582912);      // 524,288 B (dead after proj)
  __hip_bfloat16* v  = (__hip_bfloat16*)(ws + 26214400);     // 12,582,912 B
  unsigned char* z4  = (unsigned char*)ws;                   // 3,145,728 B (aliases dead A8)
  float* partial     = (float*)(ws + 12582912);              // 4,718,592 B (aliases dead W8)
  float* possim      = (float*)(ws + 17301504);              // 6144*4
  float* selfsim     = (float*)(ws + 17326080);              // 12288*4
  float* blocksum    = (float*)(ws + 17375232);              // 48*4
  float* out         = (float*)d_out;

  gather_fp8<<<dim3(1600), dim3(256), 0, stream>>>(f_seq, f_spa, W, A8, W8);
  proj_fp8<<<dim3(4, 96), dim3(256), 0, stream>>>(A8, W8, b, v);
  normalize_rows<<<dim3(3072), dim3(256), 0, stream>>>(v, z4);
  sim_fused_fp8<<<dim3(NPAIR), dim3(256), 0, stream>>>(z4, partial, possim, selfsim);
  finalize_terms<<<dim3(48), dim3(256), 0, stream>>>(partial, possim, selfsim, blocksum);
  finalize_sum<<<dim3(1), dim3(64), 0, stream>>>(blocksum, out);
}